// Round 1
// baseline (1118.608 us; speedup 1.0000x reference)
//
#include <hip/hip_runtime.h>
#include <hip/hip_bf16.h>
#include <stdint.h>
#include <stddef.h>

// SAE forward, fp32 in / fp32 out:
//   x_rec = topk32(relu((x - b_dec) @ W_enc^T + b_enc)) @ W_dec + b_dec
// B=4096, D=1024, H=32768, k=32.
//
// R5: gemm_scores rewritten from the reg-staged 128^2 2-barrier structure
// (measured ~315 TF, MfmaUtil 27%) to the 256^2 8-phase structure:
//   - global_load_lds width=16, pre-swizzled GLOBAL source + linear LDS dest,
//     XOR-swizzled ds_read (same involution both sides)
//   - double-buffered 128KB LDS, 8 waves (2Mx4N), BK=64, 16 K-tiles
//   - counted s_waitcnt vmcnt(4) at tile entry (never 0 except last tile)
//   - raw s_barrier (NOT __syncthreads -> no vmcnt(0) drain in the loop)
//   - s_setprio(1) around each 16-MFMA cluster
//   - bijective XCD blockIdx swizzle (m204)
//   - LDS-transpose epilogue -> 16B vectorized score stores (kills the
//     2.1x write amplification seen in WRITE_SIZE=271MB vs 134MB ideal)
// Workspace layout unchanged:
//   [0,8MB) xbf | [8MB,8.75MB) cand | [9MB,+Hc*2KB) Wbc | then scores[4096][Hc]

#define BROWS 4096
#define DIN   1024
#define HID   32768
#define KTOP  32
#define KC    48   // candidate count
#define PT    16   // per-thread register list length in topk

#define BM 256
#define BN 256
#define BK 64
#define NT (DIN / BK)   // 16 K-tiles

typedef short short8_t __attribute__((ext_vector_type(8)));
typedef float fx4 __attribute__((ext_vector_type(4)));

__device__ __forceinline__ unsigned short f2bf(float f) {
  unsigned u = __float_as_uint(f);
  u += 0x7FFFu + ((u >> 16) & 1u);   // RNE (no NaNs/infs in this data)
  return (unsigned short)(u >> 16);
}

// ---------------- convert one chunk of W_enc (rows [c0,c0+Hc)) fp32 -> bf16 ----------------
__global__ __launch_bounds__(256) void conv_wc(const float* __restrict__ W,
                                               unsigned short* __restrict__ Wbc, int c0) {
  int base = (blockIdx.x * 256 + threadIdx.x) * 4;  // chunk-local element
  float4 v = *(const float4*)(W + (size_t)c0 * DIN + base);
  ushort4 o;
  o.x = f2bf(v.x); o.y = f2bf(v.y); o.z = f2bf(v.z); o.w = f2bf(v.w);
  *(ushort4*)(Wbc + base) = o;
}

// ---------------- xbf = bf16(x - b_dec) ----------------
__global__ __launch_bounds__(256) void prep_x(const float* __restrict__ x,
                                              const float* __restrict__ bdec,
                                              unsigned short* __restrict__ xbf) {
  int base = (blockIdx.x * 256 + threadIdx.x) * 4;
  int col = base & (DIN - 1);
  float4 xv = *(const float4*)(x + base);
  float4 bv = *(const float4*)(bdec + col);
  ushort4 o;
  o.x = f2bf(xv.x - bv.x); o.y = f2bf(xv.y - bv.y);
  o.z = f2bf(xv.z - bv.z); o.w = f2bf(xv.w - bv.w);
  *(ushort4*)(xbf + base) = o;
}

// ---------------- init candidate keys ----------------
__global__ __launch_bounds__(256) void init_cand(unsigned* __restrict__ cand) {
  int i = blockIdx.x * 256 + threadIdx.x;
  if (i < BROWS * KC) cand[i] = 0u;
}

// ---------------- GEMM: approx scores (bf16) = relu(xbf @ Wbc^T + b_enc) ----------------
// 256x256 tile, 8 waves (2Mx4N), per-wave 128x64 output = acc[8][4] of 16x16x32.
// LDS halves (128 rows x 64 cols bf16 = 16KB): A-lo,A-hi,B-lo,B-hi per buffer.
// Stage schedule per tile t (4 phases): P1: B-lo(t+1)  P2: B-hi(t+1)
//                                       P3: A-lo(t+2)  P4: A-hi(t+2)
// t+1 goes to the OTHER buffer (free since t-1); t+2 overwrites the CURRENT
// buffer's A regions, legal only after all waves pinned their A reads (P3 mid
// barrier). Entry-of-tile wait: vmcnt(4) leaves exactly {A-lo,A-hi(t+1)} in
// flight; last tile waits vmcnt(0).

__device__ __forceinline__ void stage_half(const unsigned short* __restrict__ g0,
                                           unsigned short* l0, int t, int k0) {
  const int w6 = (t >> 6) << 6;   // wave*64 (wave-uniform)
#pragma unroll
  for (int i = 0; i < 2; ++i) {
    const int l  = i * 512 + t;          // 16B-unit index in [0,1024)
    const int r  = l >> 3;               // row in [0,128)
    const int cl = (l & 7) ^ (r & 7);    // logical k-chunk for this slot (inverse swizzle)
    const unsigned short* g = g0 + (size_t)r * DIN + k0 + cl * 8;
    unsigned short* ld = l0 + (size_t)(i * 512 + w6) * 8;   // wave-uniform base
    __builtin_amdgcn_global_load_lds((const __attribute__((address_space(1))) unsigned int*)g,
                                     (__attribute__((address_space(3))) unsigned int*)ld,
                                     16, 0, 0);
  }
}

__device__ __forceinline__ void tile_step(int tt,
                                          const unsigned short* __restrict__ Ab,
                                          const unsigned short* __restrict__ Wb,
                                          unsigned short* bc, unsigned short* bn,
                                          fx4 (&acc)[8][4],
                                          int t, int l16, int quad, int wm, int wn) {
  const int k1 = (tt + 1) * BK;
  const int k2 = (tt + 2) * BK;
  // ---- P1 ----
  if (tt < NT - 1) { asm volatile("s_waitcnt vmcnt(4)" ::: "memory"); }
  else             { asm volatile("s_waitcnt vmcnt(0)" ::: "memory"); }
  __builtin_amdgcn_s_barrier();
  const unsigned short* Ar = bc + wm * 8192;   // wave's A half (128x64)
  const unsigned short* Br = bc + 16384;       // B tile (256x64)
  short8_t a0[8], a1[8], bfv[4][2];
#pragma unroll
  for (int mt = 0; mt < 8; ++mt)
    a0[mt] = *(const short8_t*)(Ar + (mt * 16 + l16) * 64 + ((quad) ^ (l16 & 7)) * 8);
#pragma unroll
  for (int nt = 0; nt < 4; ++nt)
#pragma unroll
    for (int ks = 0; ks < 2; ++ks)
      bfv[nt][ks] = *(const short8_t*)(Br + (wn * 64 + nt * 16 + l16) * 64 +
                                       ((ks * 4 + quad) ^ (l16 & 7)) * 8);
  if (tt + 1 < NT) stage_half(Wb, bn + 16384, t, k1);              // B-lo(t+1)
  __builtin_amdgcn_s_setprio(1);
#pragma unroll
  for (int mt = 0; mt < 8; ++mt) {
    acc[mt][0] = __builtin_amdgcn_mfma_f32_16x16x32_bf16(a0[mt], bfv[0][0], acc[mt][0], 0, 0, 0);
    acc[mt][1] = __builtin_amdgcn_mfma_f32_16x16x32_bf16(a0[mt], bfv[1][0], acc[mt][1], 0, 0, 0);
  }
  __builtin_amdgcn_s_setprio(0);
  __builtin_amdgcn_s_barrier();                                    // P1 end
  // ---- P2 ----
  if (tt + 1 < NT) stage_half(Wb + 128 * DIN, bn + 24576, t, k1);  // B-hi(t+1)
  __builtin_amdgcn_s_setprio(1);
#pragma unroll
  for (int mt = 0; mt < 8; ++mt) {
    acc[mt][2] = __builtin_amdgcn_mfma_f32_16x16x32_bf16(a0[mt], bfv[2][0], acc[mt][2], 0, 0, 0);
    acc[mt][3] = __builtin_amdgcn_mfma_f32_16x16x32_bf16(a0[mt], bfv[3][0], acc[mt][3], 0, 0, 0);
  }
  __builtin_amdgcn_s_setprio(0);
  __builtin_amdgcn_s_barrier();                                    // P2 end
  // ---- P3 ----
#pragma unroll
  for (int mt = 0; mt < 8; ++mt)
    a1[mt] = *(const short8_t*)(Ar + (mt * 16 + l16) * 64 + ((4 + quad) ^ (l16 & 7)) * 8);
#pragma unroll
  for (int mt = 0; mt < 8; ++mt) { asm volatile("" : "+v"(a1[mt])); }  // pin: A reads done
  __builtin_amdgcn_sched_barrier(0);
  __builtin_amdgcn_s_barrier();               // P3 mid: ALL waves' A reads complete
  if (tt + 2 < NT) stage_half(Ab, bc, t, k2);                      // A-lo(t+2) -> current buf
  __builtin_amdgcn_s_setprio(1);
#pragma unroll
  for (int mt = 0; mt < 8; ++mt) {
    acc[mt][0] = __builtin_amdgcn_mfma_f32_16x16x32_bf16(a1[mt], bfv[0][1], acc[mt][0], 0, 0, 0);
    acc[mt][1] = __builtin_amdgcn_mfma_f32_16x16x32_bf16(a1[mt], bfv[1][1], acc[mt][1], 0, 0, 0);
  }
  __builtin_amdgcn_s_setprio(0);
  __builtin_amdgcn_s_barrier();                                    // P3 end
  // ---- P4 ----
  if (tt + 2 < NT) stage_half(Ab + 128 * DIN, bc + 8192, t, k2);   // A-hi(t+2)
  __builtin_amdgcn_s_setprio(1);
#pragma unroll
  for (int mt = 0; mt < 8; ++mt) {
    acc[mt][2] = __builtin_amdgcn_mfma_f32_16x16x32_bf16(a1[mt], bfv[2][1], acc[mt][2], 0, 0, 0);
    acc[mt][3] = __builtin_amdgcn_mfma_f32_16x16x32_bf16(a1[mt], bfv[3][1], acc[mt][3], 0, 0, 0);
  }
  __builtin_amdgcn_s_setprio(0);
  __builtin_amdgcn_s_barrier();                                    // P4 end
}

__global__ __launch_bounds__(512, 2) void gemm_scores(
    const unsigned short* __restrict__ A,     // xbf [BROWS][DIN]
    const unsigned short* __restrict__ W,     // Wbc [Hc][DIN] (chunk-local)
    const float* __restrict__ benc,           // [HID] fp32 (global)
    unsigned short* __restrict__ scores,      // [BROWS][Hc] bf16 (chunk-local)
    int Hc, int c0) {
  extern __shared__ unsigned short lds[];     // 128KB: buf0 (A 16K|B 16K sh), buf1
  const int t    = threadIdx.x;
  const int lane = t & 63;
  const int wv   = t >> 6;    // 0..7
  const int wm   = wv >> 2;   // 0..1  (M half)
  const int wn   = wv & 3;    // 0..3  (N quarter)
  const int l16  = lane & 15;
  const int quad = lane >> 4;

  // bijective XCD swizzle (m204) on flattened block id
  const int nwg  = (int)(gridDim.x * gridDim.y);
  const int orig = (int)(blockIdx.y * gridDim.x + blockIdx.x);
  const int q    = nwg >> 3, r8 = nwg & 7;
  const int xcd  = orig & 7, loc = orig >> 3;
  const int swz  = (xcd < r8 ? xcd * (q + 1) : r8 * (q + 1) + (xcd - r8) * q) + loc;
  const int bx   = swz % (int)gridDim.x;
  const int by   = swz / (int)gridDim.x;

  const int row0  = by * BM;
  const int colc0 = bx * BN;   // chunk-local
  const unsigned short* Ab = A + (size_t)row0 * DIN;
  const unsigned short* Wb = W + (size_t)colc0 * DIN;

  unsigned short* buf0 = lds;
  unsigned short* buf1 = lds + 32768;

  fx4 acc[8][4];
  fx4 zero = {0.f, 0.f, 0.f, 0.f};
#pragma unroll
  for (int i = 0; i < 8; ++i)
#pragma unroll
    for (int j = 0; j < 4; ++j) acc[i][j] = zero;

  // prologue: tile0 full (A-lo,A-hi,B-lo,B-hi) -> buf0; tile1 A-lo,A-hi -> buf1
  stage_half(Ab,            buf0,         t, 0);
  stage_half(Ab + 128*DIN,  buf0 + 8192,  t, 0);
  stage_half(Wb,            buf0 + 16384, t, 0);
  stage_half(Wb + 128*DIN,  buf0 + 24576, t, 0);
  stage_half(Ab,            buf1,         t, BK);
  stage_half(Ab + 128*DIN,  buf1 + 8192,  t, BK);

#pragma unroll 1
  for (int it = 0; it < NT / 2; ++it) {
    tile_step(2 * it,     Ab, Wb, buf0, buf1, acc, t, l16, quad, wm, wn);
    tile_step(2 * it + 1, Ab, Wb, buf1, buf0, acc, t, l16, quad, wm, wn);
  }

  // ---- epilogue: +bias, relu, bf16; LDS transpose -> 16B coalesced stores ----
  const int colbase = colc0 + wn * 64;
  float bval[4];
#pragma unroll
  for (int nt = 0; nt < 4; ++nt) bval[nt] = benc[c0 + colbase + nt * 16 + l16];

  unsigned short* et = lds;   // reuse 64KB: [128][256] bf16, quad-XOR on 16B chunks
#pragma unroll
  for (int c = 0; c < 2; ++c) {
    __syncthreads();
    if (wm == c) {
#pragma unroll
      for (int mt = 0; mt < 8; ++mt)
#pragma unroll
        for (int nt = 0; nt < 4; ++nt) {
          const int col = wn * 64 + nt * 16 + l16;
          const int ch = col >> 3, cw = col & 7;
#pragma unroll
          for (int rg = 0; rg < 4; ++rg) {
            const int row = mt * 16 + quad * 4 + rg;   // (row>>2)&3 == quad
            float v = acc[mt][nt][rg] + bval[nt];
            et[row * 256 + ((ch ^ quad) * 8) + cw] = f2bf(v > 0.f ? v : 0.f);
          }
        }
    }
    __syncthreads();
    {
      const int row = t >> 2;
      const int cb  = (t & 3) * 8;
      const int xq  = (row >> 2) & 3;
      const size_t gro = (size_t)(row0 + c * 128 + row) * Hc + colc0;
#pragma unroll
      for (int i = 0; i < 8; ++i) {
        const int ch = cb + i;
        short8_t v = *(const short8_t*)(et + row * 256 + ((ch ^ xq) * 8));
        *(short8_t*)(scores + gro + ch * 8) = v;
      }
    }
  }
}

// ---------------- top-48 candidates per row ----------------
// key = bf16bits<<16 | (0x7FFF - global_col): monotone for relu'd (>=0) bf16,
// ties -> lower col. 128 threads/row; per-thread sorted top-16 in registers
// (branchless shift-insert), wave0 merges the 128 lists -> top-48.
__global__ __launch_bounds__(128) void topk_cand(const unsigned short* __restrict__ scores,
                                                 int Hc, int c0,
                                                 unsigned* __restrict__ cand) {
  __shared__ unsigned lk[128 * 17];
  const int row = blockIdx.x;
  const int t = threadIdx.x;
  unsigned s[PT];
#pragma unroll
  for (int j = 0; j < PT; ++j) s[j] = 0u;

  const unsigned short* srow = scores + (size_t)row * Hc;
  for (int cb = t * 8; cb < Hc; cb += 128 * 8) {
    short8_t v = *(const short8_t*)(srow + cb);
    int gcb = c0 + cb;
#pragma unroll
    for (int e = 0; e < 8; ++e) {
      unsigned val = (unsigned)(unsigned short)v[e];
      unsigned key = (val << 16) | (unsigned)(0x7FFF - (gcb + e));
      if (key > s[PT - 1]) {
        unsigned prev = 0xFFFFFFFFu;
#pragma unroll
        for (int j = 0; j < PT; ++j) {
          unsigned sj = s[j];
          s[j] = (sj >= key) ? sj : (prev < key ? prev : key);
          prev = sj;
        }
      }
    }
  }
  // merge running candidates from previous chunks
  if (t < KC) {
    unsigned key = cand[row * KC + t];
    if (key > s[PT - 1]) {
      unsigned prev = 0xFFFFFFFFu;
#pragma unroll
      for (int j = 0; j < PT; ++j) {
        unsigned sj = s[j];
        s[j] = (sj >= key) ? sj : (prev < key ? prev : key);
        prev = sj;
      }
    }
  }
#pragma unroll
  for (int j = 0; j < PT; ++j) lk[t * 17 + j] = s[j];
  __syncthreads();

  if (t < 64) {
    unsigned k0 = lk[t * 17];
    unsigned k1 = lk[(t + 64) * 17];
    int h0 = 0, h1 = 0;
    unsigned mywin = 0;
    for (int it = 0; it < KC; ++it) {
      unsigned wmax = (k0 > k1) ? k0 : k1;
#pragma unroll
      for (int off = 32; off >= 1; off >>= 1) {
        unsigned o = __shfl_down(wmax, (unsigned)off);
        if (o > wmax) wmax = o;
      }
      wmax = __shfl(wmax, 0);
      if (it == t) mywin = wmax;
      if (k0 == wmax)      { ++h0; k0 = (h0 < PT) ? lk[t * 17 + h0] : 0u; }
      else if (k1 == wmax) { ++h1; k1 = (h1 < PT) ? lk[(t + 64) * 17 + h1] : 0u; }
    }
    if (t < KC) cand[row * KC + t] = mywin;
  }
}

// ---------------- fused exact rescore + top-32 select + decode ----------------
__global__ __launch_bounds__(256) void rescore_decode(
    const unsigned* __restrict__ cand,
    const float* __restrict__ x, const float* __restrict__ Wenc,
    const float* __restrict__ benc,
    const float* __restrict__ Wdec, const float* __restrict__ bdec,
    float* __restrict__ out) {
  __shared__ float xr[DIN];
  __shared__ double sc[KC];
  __shared__ int   scol[KC];
  __shared__ float fv[KTOP];
  __shared__ int   fi[KTOP];
  const int row = blockIdx.x, t = threadIdx.x;

  {
    float4 xv = *(const float4*)(x + (size_t)row * DIN + t * 4);
    float4 bv = *(const float4*)(bdec + t * 4);
    *(float4*)(xr + t * 4) = make_float4(xv.x - bv.x, xv.y - bv.y, xv.z - bv.z, xv.w - bv.w);
  }
  if (t < KC) scol[t] = 0x7FFF - (int)(cand[row * KC + t] & 0xFFFFu);
  if (t < KTOP) { fv[t] = 0.f; fi[t] = 0; }
  __syncthreads();

  const int wave = t >> 6, lane = t & 63;
  for (int j = wave; j < KC; j += 4) {
    int col = scol[j];
    const float* wr = Wenc + (size_t)col * DIN;
    double p = 0.0;
#pragma unroll
    for (int q = 0; q < 4; ++q) {
      int o = q * 256 + lane * 4;
      float4 w = *(const float4*)(wr + o);
      float4 xv = *(const float4*)(xr + o);
      p += (double)xv.x * (double)w.x + (double)xv.y * (double)w.y +
           (double)xv.z * (double)w.z + (double)xv.w * (double)w.w;
    }
#pragma unroll
    for (int off = 32; off >= 1; off >>= 1) p += __shfl_down(p, off);
    if (lane == 0) {
      double v = p + (double)benc[col];
      sc[j] = v > 0.0 ? v : 0.0;
    }
  }
  __syncthreads();

  // rank among 48 (numpy tie semantics: higher val first, then lower col)
  if (t < KC) {
    double mv = sc[t];
    int mc = scol[t];
    int rank = 0;
    for (int j = 0; j < KC; ++j) {
      double oj = sc[j];
      if (oj > mv || (oj == mv && (scol[j] < mc || (scol[j] == mc && j < t)))) ++rank;
    }
    if (rank < KTOP) { fv[rank] = (float)mv; fi[rank] = mc; }
  }
  __syncthreads();

  const int c = t * 4;
  float4 bd = *(const float4*)(bdec + c);
  float a0 = bd.x, a1 = bd.y, a2 = bd.z, a3 = bd.w;
#pragma unroll 8
  for (int j = 0; j < KTOP; ++j) {
    float v = fv[j];
    float4 w = *(const float4*)(Wdec + (size_t)fi[j] * DIN + c);
    a0 += v * w.x; a1 += v * w.y; a2 += v * w.z; a3 += v * w.w;
  }
  *(float4*)(out + (size_t)row * DIN + c) = make_float4(a0, a1, a2, a3);
}

extern "C" void kernel_launch(void* const* d_in, const int* in_sizes, int n_in,
                              void* d_out, int out_size, void* d_ws, size_t ws_size,
                              hipStream_t stream) {
  const float* x    = (const float*)d_in[0];
  const float* Wenc = (const float*)d_in[1];
  const float* benc = (const float*)d_in[2];
  const float* Wdec = (const float*)d_in[3];
  const float* bdec = (const float*)d_in[4];
  // d_in[5] is k (==32), baked into KTOP.
  float* out = (float*)d_out;

  char* ws = (char*)d_ws;
  unsigned short* xbf  = (unsigned short*)ws;                 // 8 MB
  unsigned*       cand = (unsigned*)(ws + (8u << 20));        // 768 KB

  // fit chunk size: 9MB + Hc*2048 (Wbc) + 4096*Hc*2 (scores) <= ws_size
  const size_t fixed = (size_t)(9u << 20);
  int Hc = HID;
  while (Hc > 256 &&
         fixed + (size_t)Hc * DIN * 2 + (size_t)BROWS * Hc * 2 > ws_size)
    Hc >>= 1;

  unsigned short* Wbc    = (unsigned short*)(ws + fixed);
  unsigned short* scores = (unsigned short*)(ws + fixed + (size_t)Hc * DIN * 2);

  static bool attr_set = false;
  if (!attr_set) {
    (void)hipFuncSetAttribute((const void*)gemm_scores,
                              hipFuncAttributeMaxDynamicSharedMemorySize, 131072);
    attr_set = true;
  }

  prep_x<<<BROWS * DIN / 1024, 256, 0, stream>>>(x, bdec, xbf);
  init_cand<<<(BROWS * KC + 255) / 256, 256, 0, stream>>>(cand);
  for (int c0 = 0; c0 < HID; c0 += Hc) {
    conv_wc<<<Hc, 256, 0, stream>>>(Wenc, Wbc, c0);
    gemm_scores<<<dim3(Hc / BN, BROWS / BM), 512, 131072, stream>>>(xbf, Wbc, benc, scores, Hc, c0);
    topk_cand<<<BROWS, 128, 0, stream>>>(scores, Hc, c0, cand);
  }
  rescore_decode<<<BROWS, 256, 0, stream>>>(cand, x, Wenc, benc, Wdec, bdec, out);
}

// Round 2
// 1020.224 us; speedup vs baseline: 1.0964x; 1.0964x over previous
//
#include <hip/hip_runtime.h>
#include <hip/hip_bf16.h>
#include <stdint.h>
#include <stddef.h>

// SAE forward, fp32 in / fp32 out:
//   x_rec = topk32(relu((x - b_dec) @ W_enc^T + b_enc)) @ W_dec + b_dec
// B=4096, D=1024, H=32768, k=32.
//
// R6: R5's 256^2 8-phase port spilled to scratch (VGPR_Count=128 == cap;
// WRITE_SIZE 349MB vs 134 ideal = scratch write-back) because each phase
// kept 16 b128 operands live. Restructured to fine-grained phases:
// 4 phases/tile, each {<=10 ds_read_b128 (a[8]+b[2] = 40 VGPR live);
// stage 1 half-tile; barrier; 16 MFMA; barrier}. A(t+2) staging moved to
// P4 (after P3-end barrier => all A reads structurally complete; no pins).
// Epilogue transpose buffer padded to stride 264 shorts -> conflict-free
// readout (R5 had 7.3M bank conflicts from the 16-lane/bank-group readout).

#define BROWS 4096
#define DIN   1024
#define HID   32768
#define KTOP  32
#define KC    48   // candidate count
#define PT    16   // per-thread register list length in topk

#define BM 256
#define BN 256
#define BK 64
#define NT (DIN / BK)   // 16 K-tiles
#define EP 264          // padded epilogue row stride (shorts)

typedef short short8_t __attribute__((ext_vector_type(8)));
typedef float fx4 __attribute__((ext_vector_type(4)));

__device__ __forceinline__ unsigned short f2bf(float f) {
  unsigned u = __float_as_uint(f);
  u += 0x7FFFu + ((u >> 16) & 1u);   // RNE (no NaNs/infs in this data)
  return (unsigned short)(u >> 16);
}

// ---------------- convert one chunk of W_enc (rows [c0,c0+Hc)) fp32 -> bf16 ----------------
__global__ __launch_bounds__(256) void conv_wc(const float* __restrict__ W,
                                               unsigned short* __restrict__ Wbc, int c0) {
  int base = (blockIdx.x * 256 + threadIdx.x) * 4;  // chunk-local element
  float4 v = *(const float4*)(W + (size_t)c0 * DIN + base);
  ushort4 o;
  o.x = f2bf(v.x); o.y = f2bf(v.y); o.z = f2bf(v.z); o.w = f2bf(v.w);
  *(ushort4*)(Wbc + base) = o;
}

// ---------------- xbf = bf16(x - b_dec) ----------------
__global__ __launch_bounds__(256) void prep_x(const float* __restrict__ x,
                                              const float* __restrict__ bdec,
                                              unsigned short* __restrict__ xbf) {
  int base = (blockIdx.x * 256 + threadIdx.x) * 4;
  int col = base & (DIN - 1);
  float4 xv = *(const float4*)(x + base);
  float4 bv = *(const float4*)(bdec + col);
  ushort4 o;
  o.x = f2bf(xv.x - bv.x); o.y = f2bf(xv.y - bv.y);
  o.z = f2bf(xv.z - bv.z); o.w = f2bf(xv.w - bv.w);
  *(ushort4*)(xbf + base) = o;
}

// ---------------- init candidate keys ----------------
__global__ __launch_bounds__(256) void init_cand(unsigned* __restrict__ cand) {
  int i = blockIdx.x * 256 + threadIdx.x;
  if (i < BROWS * KC) cand[i] = 0u;
}

// ---------------- GEMM: approx scores (bf16) = relu(xbf @ Wbc^T + b_enc) ----------------
// 256x256 tile, 8 waves (2Mx4N), per-wave 128x64 output = acc[8][4].
// LDS per buffer (64KB): A-lo[128x64], A-hi, B-lo, B-hi (16KB each), x2 dbuf.
// Per tile t: P1{a(ks0)+b(nt01,ks0); stage B-lo(t+1)->bn; bar; MFMA; bar}
//             P2{b(nt23,ks0);        stage B-hi(t+1)->bn; bar; MFMA; bar}
//             P3{a(ks1)+b(nt01,ks1);                      bar; MFMA; bar}
//             P4{b(nt23,ks1);        stage A(t+2)->bc x2; bar; MFMA; bar}
// Entry: vmcnt(4) (leaves A(t+1) in flight) + barrier (cross-wave DMA vis).
// A(t+2)->bc in P4 is safe: all waves' A reads happened <= P3 MFMA issue,
// which precedes the P3-end barrier.

__device__ __forceinline__ void stage_half(const unsigned short* __restrict__ g0,
                                           unsigned short* l0, int t, int k0) {
  const int w6 = (t >> 6) << 6;   // wave*64 (wave-uniform)
#pragma unroll
  for (int i = 0; i < 2; ++i) {
    const int l  = i * 512 + t;          // 16B-unit index in [0,1024)
    const int r  = l >> 3;               // row in [0,128)
    const int cl = (l & 7) ^ (r & 7);    // inverse-swizzled k-chunk for this slot
    const unsigned short* g = g0 + (size_t)r * DIN + k0 + cl * 8;
    unsigned short* ld = l0 + (size_t)(i * 512 + w6) * 8;   // wave-uniform base
    __builtin_amdgcn_global_load_lds((const __attribute__((address_space(1))) unsigned int*)g,
                                     (__attribute__((address_space(3))) unsigned int*)ld,
                                     16, 0, 0);
  }
}

__device__ __forceinline__ void tile_step(int tt,
                                          const unsigned short* __restrict__ Ab,
                                          const unsigned short* __restrict__ Wb,
                                          unsigned short* bc, unsigned short* bn,
                                          fx4 (&acc)[8][4],
                                          int t, int l16, int quad, int wm, int wn) {
  const int k1 = (tt + 1) * BK;
  const int k2 = (tt + 2) * BK;
  if (tt < NT - 1) { asm volatile("s_waitcnt vmcnt(4)" ::: "memory"); }
  else             { asm volatile("s_waitcnt vmcnt(0)" ::: "memory"); }
  __builtin_amdgcn_s_barrier();   // all waves' DMA for tile t visible

  const unsigned short* Ar = bc + wm * 8192;                     // wave's A half
  const unsigned short* Br = bc + 16384 + (wn * 64 + l16) * 64;  // +nt*1024 per frag
  const int xs = l16 & 7;
  short8_t a[8], b0, b1;

  // ---- P1: ks=0, nt={0,1} ----
#pragma unroll
  for (int mt = 0; mt < 8; ++mt)
    a[mt] = *(const short8_t*)(Ar + (mt * 16 + l16) * 64 + ((quad ^ xs) * 8));
  b0 = *(const short8_t*)(Br + 0 * 1024 + ((quad ^ xs) * 8));
  b1 = *(const short8_t*)(Br + 1 * 1024 + ((quad ^ xs) * 8));
  if (tt + 1 < NT) stage_half(Wb, bn + 16384, t, k1);            // B-lo(t+1)
  __builtin_amdgcn_s_barrier();
  __builtin_amdgcn_s_setprio(1);
#pragma unroll
  for (int mt = 0; mt < 8; ++mt)
    acc[mt][0] = __builtin_amdgcn_mfma_f32_16x16x32_bf16(a[mt], b0, acc[mt][0], 0, 0, 0);
#pragma unroll
  for (int mt = 0; mt < 8; ++mt)
    acc[mt][1] = __builtin_amdgcn_mfma_f32_16x16x32_bf16(a[mt], b1, acc[mt][1], 0, 0, 0);
  __builtin_amdgcn_s_setprio(0);
  __builtin_amdgcn_s_barrier();

  // ---- P2: ks=0, nt={2,3} ----
  b0 = *(const short8_t*)(Br + 2 * 1024 + ((quad ^ xs) * 8));
  b1 = *(const short8_t*)(Br + 3 * 1024 + ((quad ^ xs) * 8));
  if (tt + 1 < NT) stage_half(Wb + 128 * DIN, bn + 24576, t, k1); // B-hi(t+1)
  __builtin_amdgcn_s_barrier();
  __builtin_amdgcn_s_setprio(1);
#pragma unroll
  for (int mt = 0; mt < 8; ++mt)
    acc[mt][2] = __builtin_amdgcn_mfma_f32_16x16x32_bf16(a[mt], b0, acc[mt][2], 0, 0, 0);
#pragma unroll
  for (int mt = 0; mt < 8; ++mt)
    acc[mt][3] = __builtin_amdgcn_mfma_f32_16x16x32_bf16(a[mt], b1, acc[mt][3], 0, 0, 0);
  __builtin_amdgcn_s_setprio(0);
  __builtin_amdgcn_s_barrier();

  // ---- P3: ks=1, nt={0,1} ----
#pragma unroll
  for (int mt = 0; mt < 8; ++mt)
    a[mt] = *(const short8_t*)(Ar + (mt * 16 + l16) * 64 + (((4 + quad) ^ xs) * 8));
  b0 = *(const short8_t*)(Br + 0 * 1024 + (((4 + quad) ^ xs) * 8));
  b1 = *(const short8_t*)(Br + 1 * 1024 + (((4 + quad) ^ xs) * 8));
  __builtin_amdgcn_s_barrier();
  __builtin_amdgcn_s_setprio(1);
#pragma unroll
  for (int mt = 0; mt < 8; ++mt)
    acc[mt][0] = __builtin_amdgcn_mfma_f32_16x16x32_bf16(a[mt], b0, acc[mt][0], 0, 0, 0);
#pragma unroll
  for (int mt = 0; mt < 8; ++mt)
    acc[mt][1] = __builtin_amdgcn_mfma_f32_16x16x32_bf16(a[mt], b1, acc[mt][1], 0, 0, 0);
  __builtin_amdgcn_s_setprio(0);
  __builtin_amdgcn_s_barrier();   // all waves' A reads complete past this point

  // ---- P4: ks=1, nt={2,3} ----
  b0 = *(const short8_t*)(Br + 2 * 1024 + (((4 + quad) ^ xs) * 8));
  b1 = *(const short8_t*)(Br + 3 * 1024 + (((4 + quad) ^ xs) * 8));
  if (tt + 2 < NT) {
    stage_half(Ab,             bc,        t, k2);                // A-lo(t+2)
    stage_half(Ab + 128 * DIN, bc + 8192, t, k2);                // A-hi(t+2)
  }
  __builtin_amdgcn_s_barrier();
  __builtin_amdgcn_s_setprio(1);
#pragma unroll
  for (int mt = 0; mt < 8; ++mt)
    acc[mt][2] = __builtin_amdgcn_mfma_f32_16x16x32_bf16(a[mt], b0, acc[mt][2], 0, 0, 0);
#pragma unroll
  for (int mt = 0; mt < 8; ++mt)
    acc[mt][3] = __builtin_amdgcn_mfma_f32_16x16x32_bf16(a[mt], b1, acc[mt][3], 0, 0, 0);
  __builtin_amdgcn_s_setprio(0);
  __builtin_amdgcn_s_barrier();
}

__global__ __launch_bounds__(512, 2) void gemm_scores(
    const unsigned short* __restrict__ A,     // xbf [BROWS][DIN]
    const unsigned short* __restrict__ W,     // Wbc [Hc][DIN] (chunk-local)
    const float* __restrict__ benc,           // [HID] fp32 (global)
    unsigned short* __restrict__ scores,      // [BROWS][Hc] bf16 (chunk-local)
    int Hc, int c0) {
  extern __shared__ unsigned short lds[];     // 128KB: 2 x (A 32K | B 32K bytes)
  const int t    = threadIdx.x;
  const int lane = t & 63;
  const int wv   = t >> 6;    // 0..7
  const int wm   = wv >> 2;   // 0..1  (M half)
  const int wn   = wv & 3;    // 0..3  (N quarter)
  const int l16  = lane & 15;
  const int quad = lane >> 4;

  // bijective XCD swizzle (m204) on flattened block id
  const int nwg  = (int)(gridDim.x * gridDim.y);
  const int orig = (int)(blockIdx.y * gridDim.x + blockIdx.x);
  const int q    = nwg >> 3, r8 = nwg & 7;
  const int xcd  = orig & 7, loc = orig >> 3;
  const int swz  = (xcd < r8 ? xcd * (q + 1) : r8 * (q + 1) + (xcd - r8) * q) + loc;
  const int bx   = swz % (int)gridDim.x;
  const int by   = swz / (int)gridDim.x;

  const int row0  = by * BM;
  const int colc0 = bx * BN;   // chunk-local
  const unsigned short* Ab = A + (size_t)row0 * DIN;
  const unsigned short* Wb = W + (size_t)colc0 * DIN;

  unsigned short* buf0 = lds;
  unsigned short* buf1 = lds + 32768;

  fx4 acc[8][4];
  fx4 zero = {0.f, 0.f, 0.f, 0.f};
#pragma unroll
  for (int i = 0; i < 8; ++i)
#pragma unroll
    for (int j = 0; j < 4; ++j) acc[i][j] = zero;

  // prologue: tile0 full -> buf0; tile1 A halves -> buf1
  stage_half(Ab,            buf0,         t, 0);
  stage_half(Ab + 128*DIN,  buf0 + 8192,  t, 0);
  stage_half(Wb,            buf0 + 16384, t, 0);
  stage_half(Wb + 128*DIN,  buf0 + 24576, t, 0);
  stage_half(Ab,            buf1,         t, BK);
  stage_half(Ab + 128*DIN,  buf1 + 8192,  t, BK);

#pragma unroll 1
  for (int it = 0; it < NT / 2; ++it) {
    tile_step(2 * it,     Ab, Wb, buf0, buf1, acc, t, l16, quad, wm, wn);
    tile_step(2 * it + 1, Ab, Wb, buf1, buf0, acc, t, l16, quad, wm, wn);
  }

  // ---- epilogue: +bias, relu, bf16; padded-LDS transpose -> 16B stores ----
  const int colbase = colc0 + wn * 64;
  float bval[4];
#pragma unroll
  for (int nt = 0; nt < 4; ++nt) bval[nt] = benc[c0 + colbase + nt * 16 + l16];

  unsigned short* et = lds;   // reuse: [128][EP=264] shorts = 67.5KB
#pragma unroll
  for (int c = 0; c < 2; ++c) {
    __syncthreads();
    if (wm == c) {
#pragma unroll
      for (int nt = 0; nt < 4; ++nt) {
        const int col = wn * 64 + nt * 16 + l16;
#pragma unroll
        for (int mt = 0; mt < 8; ++mt)
#pragma unroll
          for (int rg = 0; rg < 4; ++rg) {
            const int row = mt * 16 + quad * 4 + rg;
            float v = acc[mt][nt][rg] + bval[nt];
            et[row * EP + col] = f2bf(v > 0.f ? v : 0.f);
          }
      }
    }
    __syncthreads();
    {
      const int row = t >> 2;
      const size_t gro = (size_t)(row0 + c * 128 + row) * Hc + colc0;
#pragma unroll
      for (int i = 0; i < 8; ++i) {
        const int ch = (t & 3) * 8 + i;   // 16B chunk 0..31
        short8_t v = *(const short8_t*)(et + row * EP + ch * 8);
        *(short8_t*)(scores + gro + ch * 8) = v;
      }
    }
  }
}

// ---------------- top-48 candidates per row ----------------
// key = bf16bits<<16 | (0x7FFF - global_col): monotone for relu'd (>=0) bf16,
// ties -> lower col. 128 threads/row; per-thread sorted top-16 in registers
// (branchless shift-insert), wave0 merges the 128 lists -> top-48.
__global__ __launch_bounds__(128) void topk_cand(const unsigned short* __restrict__ scores,
                                                 int Hc, int c0,
                                                 unsigned* __restrict__ cand) {
  __shared__ unsigned lk[128 * 17];
  const int row = blockIdx.x;
  const int t = threadIdx.x;
  unsigned s[PT];
#pragma unroll
  for (int j = 0; j < PT; ++j) s[j] = 0u;

  const unsigned short* srow = scores + (size_t)row * Hc;
  for (int cb = t * 8; cb < Hc; cb += 128 * 8) {
    short8_t v = *(const short8_t*)(srow + cb);
    int gcb = c0 + cb;
#pragma unroll
    for (int e = 0; e < 8; ++e) {
      unsigned val = (unsigned)(unsigned short)v[e];
      unsigned key = (val << 16) | (unsigned)(0x7FFF - (gcb + e));
      if (key > s[PT - 1]) {
        unsigned prev = 0xFFFFFFFFu;
#pragma unroll
        for (int j = 0; j < PT; ++j) {
          unsigned sj = s[j];
          s[j] = (sj >= key) ? sj : (prev < key ? prev : key);
          prev = sj;
        }
      }
    }
  }
  // merge running candidates from previous chunks
  if (t < KC) {
    unsigned key = cand[row * KC + t];
    if (key > s[PT - 1]) {
      unsigned prev = 0xFFFFFFFFu;
#pragma unroll
      for (int j = 0; j < PT; ++j) {
        unsigned sj = s[j];
        s[j] = (sj >= key) ? sj : (prev < key ? prev : key);
        prev = sj;
      }
    }
  }
#pragma unroll
  for (int j = 0; j < PT; ++j) lk[t * 17 + j] = s[j];
  __syncthreads();

  if (t < 64) {
    unsigned k0 = lk[t * 17];
    unsigned k1 = lk[(t + 64) * 17];
    int h0 = 0, h1 = 0;
    unsigned mywin = 0;
    for (int it = 0; it < KC; ++it) {
      unsigned wmax = (k0 > k1) ? k0 : k1;
#pragma unroll
      for (int off = 32; off >= 1; off >>= 1) {
        unsigned o = __shfl_down(wmax, (unsigned)off);
        if (o > wmax) wmax = o;
      }
      wmax = __shfl(wmax, 0);
      if (it == t) mywin = wmax;
      if (k0 == wmax)      { ++h0; k0 = (h0 < PT) ? lk[t * 17 + h0] : 0u; }
      else if (k1 == wmax) { ++h1; k1 = (h1 < PT) ? lk[(t + 64) * 17 + h1] : 0u; }
    }
    if (t < KC) cand[row * KC + t] = mywin;
  }
}

// ---------------- fused exact rescore + top-32 select + decode ----------------
__global__ __launch_bounds__(256) void rescore_decode(
    const unsigned* __restrict__ cand,
    const float* __restrict__ x, const float* __restrict__ Wenc,
    const float* __restrict__ benc,
    const float* __restrict__ Wdec, const float* __restrict__ bdec,
    float* __restrict__ out) {
  __shared__ float xr[DIN];
  __shared__ double sc[KC];
  __shared__ int   scol[KC];
  __shared__ float fv[KTOP];
  __shared__ int   fi[KTOP];
  const int row = blockIdx.x, t = threadIdx.x;

  {
    float4 xv = *(const float4*)(x + (size_t)row * DIN + t * 4);
    float4 bv = *(const float4*)(bdec + t * 4);
    *(float4*)(xr + t * 4) = make_float4(xv.x - bv.x, xv.y - bv.y, xv.z - bv.z, xv.w - bv.w);
  }
  if (t < KC) scol[t] = 0x7FFF - (int)(cand[row * KC + t] & 0xFFFFu);
  if (t < KTOP) { fv[t] = 0.f; fi[t] = 0; }
  __syncthreads();

  const int wave = t >> 6, lane = t & 63;
  for (int j = wave; j < KC; j += 4) {
    int col = scol[j];
    const float* wr = Wenc + (size_t)col * DIN;
    double p = 0.0;
#pragma unroll
    for (int q = 0; q < 4; ++q) {
      int o = q * 256 + lane * 4;
      float4 w = *(const float4*)(wr + o);
      float4 xv = *(const float4*)(xr + o);
      p += (double)xv.x * (double)w.x + (double)xv.y * (double)w.y +
           (double)xv.z * (double)w.z + (double)xv.w * (double)w.w;
    }
#pragma unroll
    for (int off = 32; off >= 1; off >>= 1) p += __shfl_down(p, off);
    if (lane == 0) {
      double v = p + (double)benc[col];
      sc[j] = v > 0.0 ? v : 0.0;
    }
  }
  __syncthreads();

  // rank among 48 (numpy tie semantics: higher val first, then lower col)
  if (t < KC) {
    double mv = sc[t];
    int mc = scol[t];
    int rank = 0;
    for (int j = 0; j < KC; ++j) {
      double oj = sc[j];
      if (oj > mv || (oj == mv && (scol[j] < mc || (scol[j] == mc && j < t)))) ++rank;
    }
    if (rank < KTOP) { fv[rank] = (float)mv; fi[rank] = mc; }
  }
  __syncthreads();

  const int c = t * 4;
  float4 bd = *(const float4*)(bdec + c);
  float a0 = bd.x, a1 = bd.y, a2 = bd.z, a3 = bd.w;
#pragma unroll 8
  for (int j = 0; j < KTOP; ++j) {
    float v = fv[j];
    float4 w = *(const float4*)(Wdec + (size_t)fi[j] * DIN + c);
    a0 += v * w.x; a1 += v * w.y; a2 += v * w.z; a3 += v * w.w;
  }
  *(float4*)(out + (size_t)row * DIN + c) = make_float4(a0, a1, a2, a3);
}

extern "C" void kernel_launch(void* const* d_in, const int* in_sizes, int n_in,
                              void* d_out, int out_size, void* d_ws, size_t ws_size,
                              hipStream_t stream) {
  const float* x    = (const float*)d_in[0];
  const float* Wenc = (const float*)d_in[1];
  const float* benc = (const float*)d_in[2];
  const float* Wdec = (const float*)d_in[3];
  const float* bdec = (const float*)d_in[4];
  // d_in[5] is k (==32), baked into KTOP.
  float* out = (float*)d_out;

  char* ws = (char*)d_ws;
  unsigned short* xbf  = (unsigned short*)ws;                 // 8 MB
  unsigned*       cand = (unsigned*)(ws + (8u << 20));        // 768 KB

  // fit chunk size: 9MB + Hc*2048 (Wbc) + 4096*Hc*2 (scores) <= ws_size
  const size_t fixed = (size_t)(9u << 20);
  int Hc = HID;
  while (Hc > 256 &&
         fixed + (size_t)Hc * DIN * 2 + (size_t)BROWS * Hc * 2 > ws_size)
    Hc >>= 1;

  unsigned short* Wbc    = (unsigned short*)(ws + fixed);
  unsigned short* scores = (unsigned short*)(ws + fixed + (size_t)Hc * DIN * 2);

  static bool attr_set = false;
  if (!attr_set) {
    (void)hipFuncSetAttribute((const void*)gemm_scores,
                              hipFuncAttributeMaxDynamicSharedMemorySize, 131072);
    attr_set = true;
  }

  prep_x<<<BROWS * DIN / 1024, 256, 0, stream>>>(x, bdec, xbf);
  init_cand<<<(BROWS * KC + 255) / 256, 256, 0, stream>>>(cand);
  for (int c0 = 0; c0 < HID; c0 += Hc) {
    conv_wc<<<Hc, 256, 0, stream>>>(Wenc, Wbc, c0);
    gemm_scores<<<dim3(Hc / BN, BROWS / BM), 512, 131072, stream>>>(xbf, Wbc, benc, scores, Hc, c0);
    topk_cand<<<BROWS, 128, 0, stream>>>(scores, Hc, c0, cand);
  }
  rescore_decode<<<BROWS, 256, 0, stream>>>(cand, x, Wenc, benc, Wdec, bdec, out);
}

// Round 3
// 1001.359 us; speedup vs baseline: 1.1171x; 1.0188x over previous
//
#include <hip/hip_runtime.h>
#include <hip/hip_bf16.h>
#include <stdint.h>
#include <stddef.h>

// SAE forward, fp32 in / fp32 out:
//   x_rec = topk32(relu((x - b_dec) @ W_enc^T + b_enc)) @ W_dec + b_dec
// B=4096, D=1024, H=32768, k=32.
//
// R7: R6 measured 14.7k cyc/tile vs a 2458-cyc matrix-pipe floor: the 9
// barriers/tile serialized ds_read drains against MFMA bursts every 16
// MFMAs. All 4 phases of a tile read the SAME LDS buffer, so only TWO
// barriers are required: entry (DMA visibility) and pre-A(t+2)-overwrite.
// Rewritten tile: 4 MFMA groups of 16 with ping-pong operand regs
// (aP/aQ/bP/bQ = 64 VGPR peak), reads of group g+1 issued before group g's
// MFMAs (compiler lgkmcnt overlaps). Also: column-major XCD chunking (R6's
// row-major streamed the full 32MB W chunk through each XCD's 4MB L2 twice
// -> FETCH 559MB ~= 8 XCD x 2 x 32MB) and 1-VGPR saddr-form DMA addressing.

#define BROWS 4096
#define DIN   1024
#define HID   32768
#define KTOP  32
#define KC    48   // candidate count
#define PT    16   // per-thread register list length in topk

#define BM 256
#define BN 256
#define BK 64
#define NT (DIN / BK)   // 16 K-tiles
#define EP 264          // padded epilogue row stride (shorts)

typedef short short8_t __attribute__((ext_vector_type(8)));
typedef float fx4 __attribute__((ext_vector_type(4)));

__device__ __forceinline__ unsigned short f2bf(float f) {
  unsigned u = __float_as_uint(f);
  u += 0x7FFFu + ((u >> 16) & 1u);   // RNE (no NaNs/infs in this data)
  return (unsigned short)(u >> 16);
}

// ---------------- convert one chunk of W_enc (rows [c0,c0+Hc)) fp32 -> bf16 ----------------
__global__ __launch_bounds__(256) void conv_wc(const float* __restrict__ W,
                                               unsigned short* __restrict__ Wbc, int c0) {
  int base = (blockIdx.x * 256 + threadIdx.x) * 4;  // chunk-local element
  float4 v = *(const float4*)(W + (size_t)c0 * DIN + base);
  ushort4 o;
  o.x = f2bf(v.x); o.y = f2bf(v.y); o.z = f2bf(v.z); o.w = f2bf(v.w);
  *(ushort4*)(Wbc + base) = o;
}

// ---------------- xbf = bf16(x - b_dec) ----------------
__global__ __launch_bounds__(256) void prep_x(const float* __restrict__ x,
                                              const float* __restrict__ bdec,
                                              unsigned short* __restrict__ xbf) {
  int base = (blockIdx.x * 256 + threadIdx.x) * 4;
  int col = base & (DIN - 1);
  float4 xv = *(const float4*)(x + base);
  float4 bv = *(const float4*)(bdec + col);
  ushort4 o;
  o.x = f2bf(xv.x - bv.x); o.y = f2bf(xv.y - bv.y);
  o.z = f2bf(xv.z - bv.z); o.w = f2bf(xv.w - bv.w);
  *(ushort4*)(xbf + base) = o;
}

// ---------------- init candidate keys ----------------
__global__ __launch_bounds__(256) void init_cand(unsigned* __restrict__ cand) {
  int i = blockIdx.x * 256 + threadIdx.x;
  if (i < BROWS * KC) cand[i] = 0u;
}

// ---------------- GEMM: approx scores (bf16) = relu(xbf @ Wbc^T + b_enc) ----------------
// 256x256 tile, 8 waves (2Mx4N), per-wave 128x64 output = acc[8][4].
// LDS per buffer (64KB): A[256x64] at +0, B[256x64] at +16384 shorts; x2 dbuf.
// Per tile t (reads all from bc):
//   {vmcnt(4); barrier}                        // tile t data visible
//   read aP(mt0-3,ks0), bP(nt0-3,ks0)
//   stage B(t+1) -> bn                         // 4 DMA
//   read aQ(mt4-7,ks0);  MFMA g1 (aP x bP)
//   read aP(mt0-3,ks1), bQ(ks1);  MFMA g2 (aQ x bP)
//   read aQ(mt4-7,ks1);  MFMA g3 (aP x bQ)
//   MFMA g4 (aQ x bQ)                          // all bc reads consumed
//   barrier
//   stage A(t+2) -> bc                         // 4 DMA (A region of current buf)
// Entry vmcnt(4) leaves the 4 newest ops (A(t+1)) in flight; last tile: vmcnt(0).

__device__ __forceinline__ void stage_pair(const unsigned short* __restrict__ g,
                                           unsigned short* l0, int voff, int w8) {
  __builtin_amdgcn_global_load_lds((const __attribute__((address_space(1))) unsigned int*)(g + voff),
                                   (__attribute__((address_space(3))) unsigned int*)(l0 + w8),
                                   16, 0, 0);
  __builtin_amdgcn_global_load_lds((const __attribute__((address_space(1))) unsigned int*)(g + voff + 64 * DIN),
                                   (__attribute__((address_space(3))) unsigned int*)(l0 + w8 + 4096),
                                   16, 0, 0);
}

__device__ __forceinline__ void tile_step(int tt,
                                          const unsigned short* __restrict__ Ab,
                                          const unsigned short* __restrict__ Wb,
                                          unsigned short* bc, unsigned short* bn,
                                          fx4 (&acc)[8][4],
                                          int voff, int w8, int l16, int quad, int wm, int wn) {
  if (tt < NT - 1) { asm volatile("s_waitcnt vmcnt(4)" ::: "memory"); }
  else             { asm volatile("s_waitcnt vmcnt(0)" ::: "memory"); }
  __builtin_amdgcn_s_barrier();   // all waves' DMA for tile t visible

  const unsigned short* Ar = bc + wm * 8192 + l16 * 64;          // + mt*1024
  const unsigned short* Br = bc + 16384 + (wn * 64 + l16) * 64;  // + nt*1024
  const int xs = l16 & 7;
  const int o0 = (quad ^ xs) * 8;
  const int o1 = ((4 + quad) ^ xs) * 8;

  short8_t aP[4], aQ[4], bP[4], bQ[4];
#pragma unroll
  for (int i = 0; i < 4; ++i) aP[i] = *(const short8_t*)(Ar + i * 1024 + o0);
#pragma unroll
  for (int i = 0; i < 4; ++i) bP[i] = *(const short8_t*)(Br + i * 1024 + o0);
  if (tt + 1 < NT) {
    stage_pair(Wb + (tt + 1) * BK,             bn + 16384, voff, w8);   // B-lo(t+1)
    stage_pair(Wb + 128 * DIN + (tt + 1) * BK, bn + 24576, voff, w8);   // B-hi(t+1)
  }
#pragma unroll
  for (int i = 0; i < 4; ++i) aQ[i] = *(const short8_t*)(Ar + (4 + i) * 1024 + o0);
  __builtin_amdgcn_s_setprio(1);
#pragma unroll
  for (int i = 0; i < 4; ++i)
#pragma unroll
    for (int nt = 0; nt < 4; ++nt)
      acc[i][nt] = __builtin_amdgcn_mfma_f32_16x16x32_bf16(aP[i], bP[nt], acc[i][nt], 0, 0, 0);
  __builtin_amdgcn_s_setprio(0);

#pragma unroll
  for (int i = 0; i < 4; ++i) aP[i] = *(const short8_t*)(Ar + i * 1024 + o1);
#pragma unroll
  for (int i = 0; i < 4; ++i) bQ[i] = *(const short8_t*)(Br + i * 1024 + o1);
  __builtin_amdgcn_s_setprio(1);
#pragma unroll
  for (int i = 0; i < 4; ++i)
#pragma unroll
    for (int nt = 0; nt < 4; ++nt)
      acc[4 + i][nt] = __builtin_amdgcn_mfma_f32_16x16x32_bf16(aQ[i], bP[nt], acc[4 + i][nt], 0, 0, 0);
  __builtin_amdgcn_s_setprio(0);

#pragma unroll
  for (int i = 0; i < 4; ++i) aQ[i] = *(const short8_t*)(Ar + (4 + i) * 1024 + o1);
  __builtin_amdgcn_s_setprio(1);
#pragma unroll
  for (int i = 0; i < 4; ++i)
#pragma unroll
    for (int nt = 0; nt < 4; ++nt)
      acc[i][nt] = __builtin_amdgcn_mfma_f32_16x16x32_bf16(aP[i], bQ[nt], acc[i][nt], 0, 0, 0);
#pragma unroll
  for (int i = 0; i < 4; ++i)
#pragma unroll
    for (int nt = 0; nt < 4; ++nt)
      acc[4 + i][nt] = __builtin_amdgcn_mfma_f32_16x16x32_bf16(aQ[i], bQ[nt], acc[4 + i][nt], 0, 0, 0);
  __builtin_amdgcn_s_setprio(0);

  __builtin_amdgcn_s_barrier();   // all waves consumed bc (A and B) for tile t
  if (tt + 2 < NT) {
    stage_pair(Ab + (tt + 2) * BK,             bc,        voff, w8);    // A-lo(t+2)
    stage_pair(Ab + 128 * DIN + (tt + 2) * BK, bc + 8192, voff, w8);    // A-hi(t+2)
  }
}

__global__ __launch_bounds__(512, 2) void gemm_scores(
    const unsigned short* __restrict__ A,     // xbf [BROWS][DIN]
    const unsigned short* __restrict__ W,     // Wbc [Hc][DIN] (chunk-local)
    const float* __restrict__ benc,           // [HID] fp32 (global)
    unsigned short* __restrict__ scores,      // [BROWS][Hc] bf16 (chunk-local)
    int Hc, int c0) {
  extern __shared__ unsigned short lds[];     // 128KB: 2 x (A 32KB | B 32KB)
  const int t    = threadIdx.x;
  const int lane = t & 63;
  const int wv   = t >> 6;    // 0..7
  const int wm   = wv >> 2;   // 0..1  (M half)
  const int wn   = wv & 3;    // 0..3  (N quarter)
  const int l16  = lane & 15;
  const int quad = lane >> 4;

  // bijective XCD swizzle (m204) on COLUMN-major flattened id: consecutive
  // per-XCD blocks share bx (same W panel) -> W stays L2-resident per XCD.
  const int gx   = (int)gridDim.x, gy = (int)gridDim.y;
  const int nwg  = gx * gy;
  const int orig = (int)blockIdx.x * gy + (int)blockIdx.y;
  const int q    = nwg >> 3, r8 = nwg & 7;
  const int xcd  = orig & 7, loc = orig >> 3;
  const int swz  = (xcd < r8 ? xcd * (q + 1) : r8 * (q + 1) + (xcd - r8) * q) + loc;
  const int bx   = swz / gy;
  const int by   = swz % gy;

  const int row0  = by * BM;
  const int colc0 = bx * BN;   // chunk-local
  const unsigned short* Ab = A + (size_t)row0 * DIN;
  const unsigned short* Wb = W + (size_t)colc0 * DIN;

  unsigned short* buf0 = lds;
  unsigned short* buf1 = lds + 32768;

  // per-lane DMA source offset (elements) and wave-uniform LDS slot (shorts)
  const int r_   = t >> 3;
  const int voff = r_ * DIN + ((t & 7) ^ (r_ & 7)) * 8;
  const int w8   = (t & ~63) * 8;

  fx4 acc[8][4];
  fx4 zero = {0.f, 0.f, 0.f, 0.f};
#pragma unroll
  for (int i = 0; i < 8; ++i)
#pragma unroll
    for (int j = 0; j < 4; ++j) acc[i][j] = zero;

  // prologue: tile0 A,B -> buf0; tile1 A -> buf1   (12 DMA ops/thread)
  stage_pair(Ab,                 buf0,         voff, w8);
  stage_pair(Ab + 128 * DIN,     buf0 + 8192,  voff, w8);
  stage_pair(Wb,                 buf0 + 16384, voff, w8);
  stage_pair(Wb + 128 * DIN,     buf0 + 24576, voff, w8);
  stage_pair(Ab + BK,            buf1,         voff, w8);
  stage_pair(Ab + 128 * DIN + BK, buf1 + 8192, voff, w8);

#pragma unroll 1
  for (int it = 0; it < NT / 2; ++it) {
    tile_step(2 * it,     Ab, Wb, buf0, buf1, acc, voff, w8, l16, quad, wm, wn);
    tile_step(2 * it + 1, Ab, Wb, buf1, buf0, acc, voff, w8, l16, quad, wm, wn);
  }

  // ---- epilogue: +bias, relu, bf16; padded-LDS transpose -> 16B stores ----
  const int colbase = colc0 + wn * 64;
  float bval[4];
#pragma unroll
  for (int nt = 0; nt < 4; ++nt) bval[nt] = benc[c0 + colbase + nt * 16 + l16];

  unsigned short* et = lds;   // reuse: [128][EP=264] shorts = 67.5KB
#pragma unroll
  for (int c = 0; c < 2; ++c) {
    __syncthreads();
    if (wm == c) {
#pragma unroll
      for (int nt = 0; nt < 4; ++nt) {
        const int col = wn * 64 + nt * 16 + l16;
#pragma unroll
        for (int mt = 0; mt < 8; ++mt)
#pragma unroll
          for (int rg = 0; rg < 4; ++rg) {
            const int row = mt * 16 + quad * 4 + rg;
            float v = acc[mt][nt][rg] + bval[nt];
            et[row * EP + col] = f2bf(v > 0.f ? v : 0.f);
          }
      }
    }
    __syncthreads();
    {
      const int row = t >> 2;
      const size_t gro = (size_t)(row0 + c * 128 + row) * Hc + colc0;
#pragma unroll
      for (int i = 0; i < 8; ++i) {
        const int ch = (t & 3) * 8 + i;   // 16B chunk 0..31
        short8_t v = *(const short8_t*)(et + row * EP + ch * 8);
        *(short8_t*)(scores + gro + ch * 8) = v;
      }
    }
  }
}

// ---------------- top-48 candidates per row ----------------
// key = bf16bits<<16 | (0x7FFF - global_col): monotone for relu'd (>=0) bf16,
// ties -> lower col. 128 threads/row; per-thread sorted top-16 in registers
// (branchless shift-insert), wave0 merges the 128 lists -> top-48.
__global__ __launch_bounds__(128) void topk_cand(const unsigned short* __restrict__ scores,
                                                 int Hc, int c0,
                                                 unsigned* __restrict__ cand) {
  __shared__ unsigned lk[128 * 17];
  const int row = blockIdx.x;
  const int t = threadIdx.x;
  unsigned s[PT];
#pragma unroll
  for (int j = 0; j < PT; ++j) s[j] = 0u;

  const unsigned short* srow = scores + (size_t)row * Hc;
  for (int cb = t * 8; cb < Hc; cb += 128 * 8) {
    short8_t v = *(const short8_t*)(srow + cb);
    int gcb = c0 + cb;
#pragma unroll
    for (int e = 0; e < 8; ++e) {
      unsigned val = (unsigned)(unsigned short)v[e];
      unsigned key = (val << 16) | (unsigned)(0x7FFF - (gcb + e));
      if (key > s[PT - 1]) {
        unsigned prev = 0xFFFFFFFFu;
#pragma unroll
        for (int j = 0; j < PT; ++j) {
          unsigned sj = s[j];
          s[j] = (sj >= key) ? sj : (prev < key ? prev : key);
          prev = sj;
        }
      }
    }
  }
  // merge running candidates from previous chunks
  if (t < KC) {
    unsigned key = cand[row * KC + t];
    if (key > s[PT - 1]) {
      unsigned prev = 0xFFFFFFFFu;
#pragma unroll
      for (int j = 0; j < PT; ++j) {
        unsigned sj = s[j];
        s[j] = (sj >= key) ? sj : (prev < key ? prev : key);
        prev = sj;
      }
    }
  }
#pragma unroll
  for (int j = 0; j < PT; ++j) lk[t * 17 + j] = s[j];
  __syncthreads();

  if (t < 64) {
    unsigned k0 = lk[t * 17];
    unsigned k1 = lk[(t + 64) * 17];
    int h0 = 0, h1 = 0;
    unsigned mywin = 0;
    for (int it = 0; it < KC; ++it) {
      unsigned wmax = (k0 > k1) ? k0 : k1;
#pragma unroll
      for (int off = 32; off >= 1; off >>= 1) {
        unsigned o = __shfl_down(wmax, (unsigned)off);
        if (o > wmax) wmax = o;
      }
      wmax = __shfl(wmax, 0);
      if (it == t) mywin = wmax;
      if (k0 == wmax)      { ++h0; k0 = (h0 < PT) ? lk[t * 17 + h0] : 0u; }
      else if (k1 == wmax) { ++h1; k1 = (h1 < PT) ? lk[(t + 64) * 17 + h1] : 0u; }
    }
    if (t < KC) cand[row * KC + t] = mywin;
  }
}

// ---------------- fused exact rescore + top-32 select + decode ----------------
__global__ __launch_bounds__(256) void rescore_decode(
    const unsigned* __restrict__ cand,
    const float* __restrict__ x, const float* __restrict__ Wenc,
    const float* __restrict__ benc,
    const float* __restrict__ Wdec, const float* __restrict__ bdec,
    float* __restrict__ out) {
  __shared__ float xr[DIN];
  __shared__ double sc[KC];
  __shared__ int   scol[KC];
  __shared__ float fv[KTOP];
  __shared__ int   fi[KTOP];
  const int row = blockIdx.x, t = threadIdx.x;

  {
    float4 xv = *(const float4*)(x + (size_t)row * DIN + t * 4);
    float4 bv = *(const float4*)(bdec + t * 4);
    *(float4*)(xr + t * 4) = make_float4(xv.x - bv.x, xv.y - bv.y, xv.z - bv.z, xv.w - bv.w);
  }
  if (t < KC) scol[t] = 0x7FFF - (int)(cand[row * KC + t] & 0xFFFFu);
  if (t < KTOP) { fv[t] = 0.f; fi[t] = 0; }
  __syncthreads();

  const int wave = t >> 6, lane = t & 63;
  for (int j = wave; j < KC; j += 4) {
    int col = scol[j];
    const float* wr = Wenc + (size_t)col * DIN;
    double p = 0.0;
#pragma unroll
    for (int q = 0; q < 4; ++q) {
      int o = q * 256 + lane * 4;
      float4 w = *(const float4*)(wr + o);
      float4 xv = *(const float4*)(xr + o);
      p += (double)xv.x * (double)w.x + (double)xv.y * (double)w.y +
           (double)xv.z * (double)w.z + (double)xv.w * (double)w.w;
    }
#pragma unroll
    for (int off = 32; off >= 1; off >>= 1) p += __shfl_down(p, off);
    if (lane == 0) {
      double v = p + (double)benc[col];
      sc[j] = v > 0.0 ? v : 0.0;
    }
  }
  __syncthreads();

  // rank among 48 (numpy tie semantics: higher val first, then lower col)
  if (t < KC) {
    double mv = sc[t];
    int mc = scol[t];
    int rank = 0;
    for (int j = 0; j < KC; ++j) {
      double oj = sc[j];
      if (oj > mv || (oj == mv && (scol[j] < mc || (scol[j] == mc && j < t)))) ++rank;
    }
    if (rank < KTOP) { fv[rank] = (float)mv; fi[rank] = mc; }
  }
  __syncthreads();

  const int c = t * 4;
  float4 bd = *(const float4*)(bdec + c);
  float a0 = bd.x, a1 = bd.y, a2 = bd.z, a3 = bd.w;
#pragma unroll 8
  for (int j = 0; j < KTOP; ++j) {
    float v = fv[j];
    float4 w = *(const float4*)(Wdec + (size_t)fi[j] * DIN + c);
    a0 += v * w.x; a1 += v * w.y; a2 += v * w.z; a3 += v * w.w;
  }
  *(float4*)(out + (size_t)row * DIN + c) = make_float4(a0, a1, a2, a3);
}

extern "C" void kernel_launch(void* const* d_in, const int* in_sizes, int n_in,
                              void* d_out, int out_size, void* d_ws, size_t ws_size,
                              hipStream_t stream) {
  const float* x    = (const float*)d_in[0];
  const float* Wenc = (const float*)d_in[1];
  const float* benc = (const float*)d_in[2];
  const float* Wdec = (const float*)d_in[3];
  const float* bdec = (const float*)d_in[4];
  // d_in[5] is k (==32), baked into KTOP.
  float* out = (float*)d_out;

  char* ws = (char*)d_ws;
  unsigned short* xbf  = (unsigned short*)ws;                 // 8 MB
  unsigned*       cand = (unsigned*)(ws + (8u << 20));        // 768 KB

  // fit chunk size: 9MB + Hc*2048 (Wbc) + 4096*Hc*2 (scores) <= ws_size
  const size_t fixed = (size_t)(9u << 20);
  int Hc = HID;
  while (Hc > 256 &&
         fixed + (size_t)Hc * DIN * 2 + (size_t)BROWS * Hc * 2 > ws_size)
    Hc >>= 1;

  unsigned short* Wbc    = (unsigned short*)(ws + fixed);
  unsigned short* scores = (unsigned short*)(ws + fixed + (size_t)Hc * DIN * 2);

  static bool attr_set = false;
  if (!attr_set) {
    (void)hipFuncSetAttribute((const void*)gemm_scores,
                              hipFuncAttributeMaxDynamicSharedMemorySize, 131072);
    attr_set = true;
  }

  prep_x<<<BROWS * DIN / 1024, 256, 0, stream>>>(x, bdec, xbf);
  init_cand<<<(BROWS * KC + 255) / 256, 256, 0, stream>>>(cand);
  for (int c0 = 0; c0 < HID; c0 += Hc) {
    conv_wc<<<Hc, 256, 0, stream>>>(Wenc, Wbc, c0);
    gemm_scores<<<dim3(Hc / BN, BROWS / BM), 512, 131072, stream>>>(xbf, Wbc, benc, scores, Hc, c0);
    topk_cand<<<BROWS, 128, 0, stream>>>(scores, Hc, c0, cand);
  }
  rescore_decode<<<BROWS, 256, 0, stream>>>(cand, x, Wenc, benc, Wdec, bdec, out);
}